// Round 1
// baseline (78.470 us; speedup 1.0000x reference)
//
#include <hip/hip_runtime.h>
#include <math.h>

#define DIM 128

__device__ __forceinline__ float reduce32(float v) {
    // butterfly reduce within each 32-lane half of the wave64
    v += __shfl_xor(v, 1);
    v += __shfl_xor(v, 2);
    v += __shfl_xor(v, 4);
    v += __shfl_xor(v, 8);
    v += __shfl_xor(v, 16);
    return v;
}

// Kernel 1: per-node projections pk[n] = h[n]·W[0:128], pi[n] = h[n]·W[128:256]
// 32 lanes per node, float4 per lane.
__global__ void node_proj_kernel(const float* __restrict__ h,
                                 const float* __restrict__ W,
                                 float* __restrict__ pk,
                                 float* __restrict__ pi,
                                 int n_nodes) {
    int tid  = blockIdx.x * blockDim.x + threadIdx.x;
    int node = tid >> 5;
    int l    = tid & 31;
    if (node >= n_nodes) return;

    const float4 hv = *reinterpret_cast<const float4*>(h + (size_t)node * DIM + 4 * l);
    const float4 wk = *reinterpret_cast<const float4*>(W + 4 * l);
    const float4 wi = *reinterpret_cast<const float4*>(W + DIM + 4 * l);

    float sk = hv.x * wk.x + hv.y * wk.y + hv.z * wk.z + hv.w * wk.w;
    float si = hv.x * wi.x + hv.y * wi.y + hv.z * wi.z + hv.w * wi.w;
    sk = reduce32(sk);
    si = reduce32(si);
    if (l == 0) {
        pk[node] = sk;
        pi[node] = si;
    }
}

// Kernel 2: per-edge logit = e[edge]·We + pk[src] + pi[dst] + b; out = sigmoid(logit)
// 32 lanes per edge, float4 per lane.
__global__ void edge_kernel(const float* __restrict__ e,
                            const int* __restrict__ src,
                            const int* __restrict__ dst,
                            const float* __restrict__ W,
                            const float* __restrict__ b,
                            const float* __restrict__ pk,
                            const float* __restrict__ pi,
                            float* __restrict__ out,
                            int n_edges) {
    int tid  = blockIdx.x * blockDim.x + threadIdx.x;
    int edge = tid >> 5;
    int l    = tid & 31;
    if (edge >= n_edges) return;

    const float4 ev = *reinterpret_cast<const float4*>(e + (size_t)edge * DIM + 4 * l);
    const float4 we = *reinterpret_cast<const float4*>(W + 2 * DIM + 4 * l);

    float s = ev.x * we.x + ev.y * we.y + ev.z * we.z + ev.w * we.w;
    s = reduce32(s);

    if (l == 0) {
        float logit = s + pk[src[edge]] + pi[dst[edge]] + b[0];
        out[edge] = 1.0f / (1.0f + expf(-logit));
    }
}

// Fallback (only if ws_size is too small): fully fused, gathers h rows per edge.
__global__ void edge_fused_kernel(const float* __restrict__ h,
                                  const float* __restrict__ e,
                                  const int* __restrict__ src,
                                  const int* __restrict__ dst,
                                  const float* __restrict__ W,
                                  const float* __restrict__ b,
                                  float* __restrict__ out,
                                  int n_edges) {
    int tid  = blockIdx.x * blockDim.x + threadIdx.x;
    int edge = tid >> 5;
    int l    = tid & 31;
    if (edge >= n_edges) return;

    int s_idx = src[edge];
    int d_idx = dst[edge];

    const float4 hk = *reinterpret_cast<const float4*>(h + (size_t)s_idx * DIM + 4 * l);
    const float4 hi = *reinterpret_cast<const float4*>(h + (size_t)d_idx * DIM + 4 * l);
    const float4 ev = *reinterpret_cast<const float4*>(e + (size_t)edge * DIM + 4 * l);
    const float4 wk = *reinterpret_cast<const float4*>(W + 4 * l);
    const float4 wi = *reinterpret_cast<const float4*>(W + DIM + 4 * l);
    const float4 we = *reinterpret_cast<const float4*>(W + 2 * DIM + 4 * l);

    float s = hk.x * wk.x + hk.y * wk.y + hk.z * wk.z + hk.w * wk.w
            + hi.x * wi.x + hi.y * wi.y + hi.z * wi.z + hi.w * wi.w
            + ev.x * we.x + ev.y * we.y + ev.z * we.z + ev.w * we.w;
    s = reduce32(s);

    if (l == 0) {
        float logit = s + b[0];
        out[edge] = 1.0f / (1.0f + expf(-logit));
    }
}

extern "C" void kernel_launch(void* const* d_in, const int* in_sizes, int n_in,
                              void* d_out, int out_size, void* d_ws, size_t ws_size,
                              hipStream_t stream) {
    const float* h   = (const float*)d_in[0];
    const float* e   = (const float*)d_in[1];
    const int*   src = (const int*)d_in[2];
    const int*   dst = (const int*)d_in[3];
    const float* W   = (const float*)d_in[4];
    const float* b   = (const float*)d_in[5];
    float* out = (float*)d_out;

    const int n_nodes = in_sizes[0] / DIM;
    const int n_edges = in_sizes[2];

    const size_t ws_needed = 2 * (size_t)n_nodes * sizeof(float);

    if (ws_size >= ws_needed) {
        float* pk = (float*)d_ws;
        float* pi = pk + n_nodes;

        {
            int total = n_nodes * 32;
            int block = 256;
            int grid  = (total + block - 1) / block;
            node_proj_kernel<<<grid, block, 0, stream>>>(h, W, pk, pi, n_nodes);
        }
        {
            int total = n_edges * 32;
            int block = 256;
            int grid  = (total + block - 1) / block;
            edge_kernel<<<grid, block, 0, stream>>>(e, src, dst, W, b, pk, pi, out, n_edges);
        }
    } else {
        int total = n_edges * 32;
        int block = 256;
        int grid  = (total + block - 1) / block;
        edge_fused_kernel<<<grid, block, 0, stream>>>(h, e, src, dst, W, b, out, n_edges);
    }
}

// Round 3
// 66.817 us; speedup vs baseline: 1.1744x; 1.1744x over previous
//
#include <hip/hip_runtime.h>
#include <math.h>

#define DIM 128

// native clang vector type — required by __builtin_nontemporal_load
typedef float vfloat4 __attribute__((ext_vector_type(4)));

__device__ __forceinline__ float reduce16(float v) {
    // butterfly reduce within each 16-lane group of the wave64
    v += __shfl_xor(v, 1);
    v += __shfl_xor(v, 2);
    v += __shfl_xor(v, 4);
    v += __shfl_xor(v, 8);
    return v;
}

// Kernel 1: per-node projections pk[n] = h[n]·W[0:128], pi[n] = h[n]·W[128:256]
// 16 lanes per node, 8 floats (2x vfloat4) per lane, grid-stride.
__global__ __launch_bounds__(256) void node_proj_kernel(
        const float* __restrict__ h,
        const float* __restrict__ W,
        float* __restrict__ pk,
        float* __restrict__ pi,
        int n_nodes) {
    const int l = threadIdx.x & 15;
    const int group0 = (blockIdx.x * blockDim.x + threadIdx.x) >> 4;
    const int ngroups = (gridDim.x * blockDim.x) >> 4;

    // W fragments live in registers across the whole grid-stride loop
    const vfloat4 wk0 = *reinterpret_cast<const vfloat4*>(W + 8 * l);
    const vfloat4 wk1 = *reinterpret_cast<const vfloat4*>(W + 8 * l + 4);
    const vfloat4 wi0 = *reinterpret_cast<const vfloat4*>(W + DIM + 8 * l);
    const vfloat4 wi1 = *reinterpret_cast<const vfloat4*>(W + DIM + 8 * l + 4);

    for (int node = group0; node < n_nodes; node += ngroups) {
        const float* hp = h + (size_t)node * DIM + 8 * l;
        const vfloat4 h0 = __builtin_nontemporal_load(reinterpret_cast<const vfloat4*>(hp));
        const vfloat4 h1 = __builtin_nontemporal_load(reinterpret_cast<const vfloat4*>(hp + 4));

        float sk = h0.x * wk0.x + h0.y * wk0.y + h0.z * wk0.z + h0.w * wk0.w
                 + h1.x * wk1.x + h1.y * wk1.y + h1.z * wk1.z + h1.w * wk1.w;
        float si = h0.x * wi0.x + h0.y * wi0.y + h0.z * wi0.z + h0.w * wi0.w
                 + h1.x * wi1.x + h1.y * wi1.y + h1.z * wi1.z + h1.w * wi1.w;
        sk = reduce16(sk);
        si = reduce16(si);
        if (l == 0) {
            pk[node] = sk;
            pi[node] = si;
        }
    }
}

// Kernel 2: per-edge logit = e[edge]·We + pk[src] + pi[dst] + b; out = sigmoid(logit)
// 16 lanes per edge, 8 floats per lane, grid-stride. Gathers issued BEFORE the
// dot-product so their latency hides under the streaming loads.
__global__ __launch_bounds__(256) void edge_kernel(
        const float* __restrict__ e,
        const int* __restrict__ src,
        const int* __restrict__ dst,
        const float* __restrict__ W,
        const float* __restrict__ b,
        const float* __restrict__ pk,
        const float* __restrict__ pi,
        float* __restrict__ out,
        int n_edges) {
    const int l = threadIdx.x & 15;
    const int group0 = (blockIdx.x * blockDim.x + threadIdx.x) >> 4;
    const int ngroups = (gridDim.x * blockDim.x) >> 4;

    const vfloat4 we0 = *reinterpret_cast<const vfloat4*>(W + 2 * DIM + 8 * l);
    const vfloat4 we1 = *reinterpret_cast<const vfloat4*>(W + 2 * DIM + 8 * l + 4);
    const float b0 = b[0];

    for (int edge = group0; edge < n_edges; edge += ngroups) {
        // issue gather chain early (wave-broadcast loads, all 16 lanes same addr)
        const int s_idx = src[edge];
        const int d_idx = dst[edge];
        const float pkv = pk[s_idx];
        const float piv = pi[d_idx];

        const float* ep = e + (size_t)edge * DIM + 8 * l;
        const vfloat4 e0 = __builtin_nontemporal_load(reinterpret_cast<const vfloat4*>(ep));
        const vfloat4 e1 = __builtin_nontemporal_load(reinterpret_cast<const vfloat4*>(ep + 4));

        float s = e0.x * we0.x + e0.y * we0.y + e0.z * we0.z + e0.w * we0.w
                + e1.x * we1.x + e1.y * we1.y + e1.z * we1.z + e1.w * we1.w;
        s = reduce16(s);

        if (l == 0) {
            const float logit = s + pkv + piv + b0;
            out[edge] = 1.0f / (1.0f + __expf(-logit));
        }
    }
}

// Fallback (only if ws_size is too small): fully fused, gathers h rows per edge.
__global__ void edge_fused_kernel(const float* __restrict__ h,
                                  const float* __restrict__ e,
                                  const int* __restrict__ src,
                                  const int* __restrict__ dst,
                                  const float* __restrict__ W,
                                  const float* __restrict__ b,
                                  float* __restrict__ out,
                                  int n_edges) {
    int tid  = blockIdx.x * blockDim.x + threadIdx.x;
    int edge = tid >> 5;
    int l    = tid & 31;
    if (edge >= n_edges) return;

    int s_idx = src[edge];
    int d_idx = dst[edge];

    const float4 hk = *reinterpret_cast<const float4*>(h + (size_t)s_idx * DIM + 4 * l);
    const float4 hi = *reinterpret_cast<const float4*>(h + (size_t)d_idx * DIM + 4 * l);
    const float4 ev = *reinterpret_cast<const float4*>(e + (size_t)edge * DIM + 4 * l);
    const float4 wk = *reinterpret_cast<const float4*>(W + 4 * l);
    const float4 wi = *reinterpret_cast<const float4*>(W + DIM + 4 * l);
    const float4 we = *reinterpret_cast<const float4*>(W + 2 * DIM + 4 * l);

    float s = hk.x * wk.x + hk.y * wk.y + hk.z * wk.z + hk.w * wk.w
            + hi.x * wi.x + hi.y * wi.y + hi.z * wi.z + hi.w * wi.w
            + ev.x * we.x + ev.y * we.y + ev.z * we.z + ev.w * we.w;
    s += __shfl_xor(s, 1);
    s += __shfl_xor(s, 2);
    s += __shfl_xor(s, 4);
    s += __shfl_xor(s, 8);
    s += __shfl_xor(s, 16);

    if (l == 0) {
        float logit = s + b[0];
        out[edge] = 1.0f / (1.0f + expf(-logit));
    }
}

extern "C" void kernel_launch(void* const* d_in, const int* in_sizes, int n_in,
                              void* d_out, int out_size, void* d_ws, size_t ws_size,
                              hipStream_t stream) {
    const float* h   = (const float*)d_in[0];
    const float* e   = (const float*)d_in[1];
    const int*   src = (const int*)d_in[2];
    const int*   dst = (const int*)d_in[3];
    const float* W   = (const float*)d_in[4];
    const float* b   = (const float*)d_in[5];
    float* out = (float*)d_out;

    const int n_nodes = in_sizes[0] / DIM;
    const int n_edges = in_sizes[2];

    const size_t ws_needed = 2 * (size_t)n_nodes * sizeof(float);

    if (ws_size >= ws_needed) {
        float* pk = (float*)d_ws;
        float* pi = pk + n_nodes;

        {
            const int block = 256;
            int grid = (n_nodes * 16 + block - 1) / block;
            if (grid > 2048) grid = 2048;
            node_proj_kernel<<<grid, block, 0, stream>>>(h, W, pk, pi, n_nodes);
        }
        {
            const int block = 256;
            long total = (long)n_edges * 16;
            int grid = (int)((total + block - 1) / block);
            if (grid > 2048) grid = 2048;
            edge_kernel<<<grid, block, 0, stream>>>(e, src, dst, W, b, pk, pi, out, n_edges);
        }
    } else {
        int total = n_edges * 32;
        int block = 256;
        int grid  = (total + block - 1) / block;
        edge_fused_kernel<<<grid, block, 0, stream>>>(h, e, src, dst, W, b, out, n_edges);
    }
}

// Round 4
// 51.737 us; speedup vs baseline: 1.5167x; 1.2915x over previous
//
#include <hip/hip_runtime.h>
#include <math.h>

#define DIM 128

// native clang vector types — required by __builtin_nontemporal_load / packed stores
typedef float vfloat4 __attribute__((ext_vector_type(4)));
typedef float vfloat2 __attribute__((ext_vector_type(2)));

__device__ __forceinline__ float reduce16(float v) {
    // butterfly reduce within each 16-lane group of the wave64 (result in all lanes)
    v += __shfl_xor(v, 1);
    v += __shfl_xor(v, 2);
    v += __shfl_xor(v, 4);
    v += __shfl_xor(v, 8);
    return v;
}

__device__ __forceinline__ float dp4(vfloat4 a, vfloat4 b) {
    return a.x * b.x + a.y * b.y + a.z * b.z + a.w * b.w;
}

__device__ __forceinline__ vfloat4 ntload(const float* p) {
    return __builtin_nontemporal_load(reinterpret_cast<const vfloat4*>(p));
}

// Kernel 1: per-node projections pk[n] = h[n]·W[0:128], pi[n] = h[n]·W[128:256]
// 16 lanes/node; lane l covers floats [4l,4l+4) and [64+4l,64+4l+4) so every
// vector-load instruction is a contiguous 256B block. 2 nodes per iteration.
__global__ __launch_bounds__(256) void node_proj_kernel(
        const float* __restrict__ h,
        const float* __restrict__ W,
        float* __restrict__ pk,
        float* __restrict__ pi,
        int n_nodes) {
    const int l = threadIdx.x & 15;
    const int group0 = (blockIdx.x * blockDim.x + threadIdx.x) >> 4;
    const int ngroups = (gridDim.x * blockDim.x) >> 4;

    const vfloat4 wk0 = *reinterpret_cast<const vfloat4*>(W + 4 * l);
    const vfloat4 wk1 = *reinterpret_cast<const vfloat4*>(W + 64 + 4 * l);
    const vfloat4 wi0 = *reinterpret_cast<const vfloat4*>(W + DIM + 4 * l);
    const vfloat4 wi1 = *reinterpret_cast<const vfloat4*>(W + DIM + 64 + 4 * l);

    for (int base = 2 * group0; base < n_nodes; base += 2 * ngroups) {
        const int bv = (base + 1 < n_nodes);
        const float* hA = h + (size_t)base * DIM;
        const float* hB = hA + (bv ? DIM : 0);

        const vfloat4 a0 = ntload(hA + 4 * l);
        const vfloat4 a1 = ntload(hA + 64 + 4 * l);
        const vfloat4 c0 = ntload(hB + 4 * l);
        const vfloat4 c1 = ntload(hB + 64 + 4 * l);

        float skA = dp4(a0, wk0) + dp4(a1, wk1);
        float siA = dp4(a0, wi0) + dp4(a1, wi1);
        float skB = dp4(c0, wk0) + dp4(c1, wk1);
        float siB = dp4(c0, wi0) + dp4(c1, wi1);

        skA = reduce16(skA);
        siA = reduce16(siA);
        skB = reduce16(skB);
        siB = reduce16(siB);

        if (l == 0) {
            if (bv) {
                vfloat2 vk; vk.x = skA; vk.y = skB;
                vfloat2 vi; vi.x = siA; vi.y = siB;
                *reinterpret_cast<vfloat2*>(pk + base) = vk;  // base even -> 8B aligned
                *reinterpret_cast<vfloat2*>(pi + base) = vi;
            } else {
                pk[base] = skA;
                pi[base] = siA;
            }
        }
    }
}

// Kernel 2: per-edge logit = e[edge]·We + pk[src] + pi[dst] + b; out = sigmoid(logit).
// 16 lanes/edge, contiguous-per-instruction layout, 2 edges per iteration so two
// independent gather chains + 4 streaming loads are in flight per lane.
__global__ __launch_bounds__(256) void edge_kernel(
        const float* __restrict__ e,
        const int* __restrict__ src,
        const int* __restrict__ dst,
        const float* __restrict__ W,
        const float* __restrict__ b,
        const float* __restrict__ pk,
        const float* __restrict__ pi,
        float* __restrict__ out,
        int n_edges) {
    const int l = threadIdx.x & 15;
    const int group0 = (blockIdx.x * blockDim.x + threadIdx.x) >> 4;
    const int ngroups = (gridDim.x * blockDim.x) >> 4;

    const vfloat4 we0 = *reinterpret_cast<const vfloat4*>(W + 2 * DIM + 4 * l);
    const vfloat4 we1 = *reinterpret_cast<const vfloat4*>(W + 2 * DIM + 64 + 4 * l);
    const float b0 = b[0];

    for (long base = 2 * (long)group0; base < n_edges; base += 2 * (long)ngroups) {
        const int bv = (base + 1 < n_edges);
        const int iB = bv ? 1 : 0;

        // issue index + gather chains early (independent for A and B)
        const int sA = src[base];
        const int dA = dst[base];
        const int sB = src[base + iB];
        const int dB = dst[base + iB];
        const float pkA = pk[sA];
        const float piA = pi[dA];
        const float pkB = pk[sB];
        const float piB = pi[dB];

        const float* eA = e + (size_t)base * DIM;
        const float* eB = eA + (bv ? DIM : 0);
        const vfloat4 a0 = ntload(eA + 4 * l);
        const vfloat4 a1 = ntload(eA + 64 + 4 * l);
        const vfloat4 c0 = ntload(eB + 4 * l);
        const vfloat4 c1 = ntload(eB + 64 + 4 * l);

        float sAcc = dp4(a0, we0) + dp4(a1, we1);
        float sBcc = dp4(c0, we0) + dp4(c1, we1);
        sAcc = reduce16(sAcc);
        sBcc = reduce16(sBcc);

        if (l == 0) {
            const float la = sAcc + pkA + piA + b0;
            const float oa = 1.0f / (1.0f + __expf(-la));
            if (bv) {
                const float lb = sBcc + pkB + piB + b0;
                const float ob = 1.0f / (1.0f + __expf(-lb));
                vfloat2 o; o.x = oa; o.y = ob;
                *reinterpret_cast<vfloat2*>(out + base) = o;  // base even -> 8B aligned
            } else {
                out[base] = oa;
            }
        }
    }
}

// Fallback (only if ws_size is too small): fully fused, gathers h rows per edge.
__global__ void edge_fused_kernel(const float* __restrict__ h,
                                  const float* __restrict__ e,
                                  const int* __restrict__ src,
                                  const int* __restrict__ dst,
                                  const float* __restrict__ W,
                                  const float* __restrict__ b,
                                  float* __restrict__ out,
                                  int n_edges) {
    int tid  = blockIdx.x * blockDim.x + threadIdx.x;
    int edge = tid >> 5;
    int l    = tid & 31;
    if (edge >= n_edges) return;

    int s_idx = src[edge];
    int d_idx = dst[edge];

    const float4 hk = *reinterpret_cast<const float4*>(h + (size_t)s_idx * DIM + 4 * l);
    const float4 hi = *reinterpret_cast<const float4*>(h + (size_t)d_idx * DIM + 4 * l);
    const float4 ev = *reinterpret_cast<const float4*>(e + (size_t)edge * DIM + 4 * l);
    const float4 wk = *reinterpret_cast<const float4*>(W + 4 * l);
    const float4 wi = *reinterpret_cast<const float4*>(W + DIM + 4 * l);
    const float4 we = *reinterpret_cast<const float4*>(W + 2 * DIM + 4 * l);

    float s = hk.x * wk.x + hk.y * wk.y + hk.z * wk.z + hk.w * wk.w
            + hi.x * wi.x + hi.y * wi.y + hi.z * wi.z + hi.w * wi.w
            + ev.x * we.x + ev.y * we.y + ev.z * we.z + ev.w * we.w;
    s += __shfl_xor(s, 1);
    s += __shfl_xor(s, 2);
    s += __shfl_xor(s, 4);
    s += __shfl_xor(s, 8);
    s += __shfl_xor(s, 16);

    if (l == 0) {
        float logit = s + b[0];
        out[edge] = 1.0f / (1.0f + expf(-logit));
    }
}

extern "C" void kernel_launch(void* const* d_in, const int* in_sizes, int n_in,
                              void* d_out, int out_size, void* d_ws, size_t ws_size,
                              hipStream_t stream) {
    const float* h   = (const float*)d_in[0];
    const float* e   = (const float*)d_in[1];
    const int*   src = (const int*)d_in[2];
    const int*   dst = (const int*)d_in[3];
    const float* W   = (const float*)d_in[4];
    const float* b   = (const float*)d_in[5];
    float* out = (float*)d_out;

    const int n_nodes = in_sizes[0] / DIM;
    const int n_edges = in_sizes[2];

    const size_t ws_needed = 2 * (size_t)n_nodes * sizeof(float);

    if (ws_size >= ws_needed) {
        float* pk = (float*)d_ws;
        float* pi = pk + n_nodes;

        {
            const int block = 256;
            // 16 lanes per node, 2 nodes per group-iteration
            long total = ((long)n_nodes + 1) / 2 * 16;
            int grid = (int)((total + block - 1) / block);
            if (grid > 2048) grid = 2048;
            node_proj_kernel<<<grid, block, 0, stream>>>(h, W, pk, pi, n_nodes);
        }
        {
            const int block = 256;
            long total = ((long)n_edges + 1) / 2 * 16;
            int grid = (int)((total + block - 1) / block);
            if (grid > 2048) grid = 2048;
            edge_kernel<<<grid, block, 0, stream>>>(e, src, dst, W, b, pk, pi, out, n_edges);
        }
    } else {
        int total = n_edges * 32;
        int block = 256;
        int grid  = (total + block - 1) / block;
        edge_fused_kernel<<<grid, block, 0, stream>>>(h, e, src, dst, W, b, out, n_edges);
    }
}

// Round 5
// 50.793 us; speedup vs baseline: 1.5449x; 1.0186x over previous
//
#include <hip/hip_runtime.h>
#include <math.h>

#define DIM 128

// native clang vector types — required by __builtin_nontemporal_load / packed stores
typedef float vfloat4 __attribute__((ext_vector_type(4)));
typedef int   vint4   __attribute__((ext_vector_type(4)));

__device__ __forceinline__ float reduce16(float v) {
    // butterfly reduce within each 16-lane group of the wave64 (result in all lanes)
    v += __shfl_xor(v, 1);
    v += __shfl_xor(v, 2);
    v += __shfl_xor(v, 4);
    v += __shfl_xor(v, 8);
    return v;
}

__device__ __forceinline__ float dp4(vfloat4 a, vfloat4 b) {
    return a.x * b.x + a.y * b.y + a.z * b.z + a.w * b.w;
}

__device__ __forceinline__ vfloat4 ntload(const float* p) {
    return __builtin_nontemporal_load(reinterpret_cast<const vfloat4*>(p));
}

// Kernel 1: per-node projections pk[n] = h[n]·W[0:128], pi[n] = h[n]·W[128:256]
// 16 lanes/node; lane l covers floats [4l,4l+4) and [64+4l,64+4l+4). 4 nodes/iter.
__global__ __launch_bounds__(256) void node_proj_kernel(
        const float* __restrict__ h,
        const float* __restrict__ W,
        float* __restrict__ pk,
        float* __restrict__ pi,
        int n_nodes) {
    const int l = threadIdx.x & 15;
    const int group0 = (blockIdx.x * blockDim.x + threadIdx.x) >> 4;
    const int ngroups = (gridDim.x * blockDim.x) >> 4;

    const vfloat4 wk0 = *reinterpret_cast<const vfloat4*>(W + 4 * l);
    const vfloat4 wk1 = *reinterpret_cast<const vfloat4*>(W + 64 + 4 * l);
    const vfloat4 wi0 = *reinterpret_cast<const vfloat4*>(W + DIM + 4 * l);
    const vfloat4 wi1 = *reinterpret_cast<const vfloat4*>(W + DIM + 64 + 4 * l);

    // full quads (no bounds checks), then a scalar tail pass
    const int n_full = n_nodes & ~3;

    for (int base = 4 * group0; base < n_full; base += 4 * ngroups) {
        const float* hp = h + (size_t)base * DIM;
        vfloat4 a0[4], a1[4];
#pragma unroll
        for (int j = 0; j < 4; ++j) {
            a0[j] = ntload(hp + (size_t)j * DIM + 4 * l);
            a1[j] = ntload(hp + (size_t)j * DIM + 64 + 4 * l);
        }
        float sk[4], si[4];
#pragma unroll
        for (int j = 0; j < 4; ++j) {
            sk[j] = reduce16(dp4(a0[j], wk0) + dp4(a1[j], wk1));
            si[j] = reduce16(dp4(a0[j], wi0) + dp4(a1[j], wi1));
        }
        if (l == 0) {
            vfloat4 vk; vk.x = sk[0]; vk.y = sk[1]; vk.z = sk[2]; vk.w = sk[3];
            vfloat4 vi; vi.x = si[0]; vi.y = si[1]; vi.z = si[2]; vi.w = si[3];
            *reinterpret_cast<vfloat4*>(pk + base) = vk;  // base%4==0 -> 16B aligned
            *reinterpret_cast<vfloat4*>(pi + base) = vi;
        }
    }
    // tail (< 4 nodes), handled by the first groups
    for (int node = n_full + group0; node < n_nodes; node += ngroups) {
        const float* hp = h + (size_t)node * DIM;
        const vfloat4 a0 = ntload(hp + 4 * l);
        const vfloat4 a1 = ntload(hp + 64 + 4 * l);
        float sk = reduce16(dp4(a0, wk0) + dp4(a1, wk1));
        float si = reduce16(dp4(a0, wi0) + dp4(a1, wi1));
        if (l == 0) { pk[node] = sk; pi[node] = si; }
    }
}

// Kernel 2: per-edge logit = e[edge]·We + pk[src] + pi[dst] + b; out = sigmoid(logit).
// 16 lanes/edge, 4 edges/iter: 8 independent streaming loads + 4 gather chains
// in flight per lane; src/dst read as one int4 each; 16B output store.
__global__ __launch_bounds__(256) void edge_kernel(
        const float* __restrict__ e,
        const int* __restrict__ src,
        const int* __restrict__ dst,
        const float* __restrict__ W,
        const float* __restrict__ b,
        const float* __restrict__ pk,
        const float* __restrict__ pi,
        float* __restrict__ out,
        int n_edges) {
    const int l = threadIdx.x & 15;
    const int group0 = (blockIdx.x * blockDim.x + threadIdx.x) >> 4;
    const int ngroups = (gridDim.x * blockDim.x) >> 4;

    const vfloat4 we0 = *reinterpret_cast<const vfloat4*>(W + 2 * DIM + 4 * l);
    const vfloat4 we1 = *reinterpret_cast<const vfloat4*>(W + 2 * DIM + 64 + 4 * l);
    const float b0 = b[0];

    const int n_full = n_edges & ~3;

    for (int base = 4 * group0; base < n_full; base += 4 * ngroups) {
        // one 16B broadcast load each for 4 edges' indices; gathers issued early
        const vint4 s4 = *reinterpret_cast<const vint4*>(src + base);
        const vint4 d4 = *reinterpret_cast<const vint4*>(dst + base);
        float pkv[4], piv[4];
        pkv[0] = pk[s4.x]; pkv[1] = pk[s4.y]; pkv[2] = pk[s4.z]; pkv[3] = pk[s4.w];
        piv[0] = pi[d4.x]; piv[1] = pi[d4.y]; piv[2] = pi[d4.z]; piv[3] = pi[d4.w];

        const float* ep = e + (size_t)base * DIM;
        vfloat4 a0[4], a1[4];
#pragma unroll
        for (int j = 0; j < 4; ++j) {
            a0[j] = ntload(ep + (size_t)j * DIM + 4 * l);
            a1[j] = ntload(ep + (size_t)j * DIM + 64 + 4 * l);
        }

        float s[4];
#pragma unroll
        for (int j = 0; j < 4; ++j)
            s[j] = reduce16(dp4(a0[j], we0) + dp4(a1[j], we1));

        if (l == 0) {
            vfloat4 o;
            o.x = 1.0f / (1.0f + __expf(-(s[0] + pkv[0] + piv[0] + b0)));
            o.y = 1.0f / (1.0f + __expf(-(s[1] + pkv[1] + piv[1] + b0)));
            o.z = 1.0f / (1.0f + __expf(-(s[2] + pkv[2] + piv[2] + b0)));
            o.w = 1.0f / (1.0f + __expf(-(s[3] + pkv[3] + piv[3] + b0)));
            *reinterpret_cast<vfloat4*>(out + base) = o;  // base%4==0 -> 16B aligned
        }
    }
    // tail (< 4 edges)
    for (int edge = n_full + group0; edge < n_edges; edge += ngroups) {
        const int si_ = src[edge];
        const int di_ = dst[edge];
        const float pkv = pk[si_];
        const float piv = pi[di_];
        const float* ep = e + (size_t)edge * DIM;
        const vfloat4 a0 = ntload(ep + 4 * l);
        const vfloat4 a1 = ntload(ep + 64 + 4 * l);
        float s = reduce16(dp4(a0, we0) + dp4(a1, we1));
        if (l == 0) {
            out[edge] = 1.0f / (1.0f + __expf(-(s + pkv + piv + b0)));
        }
    }
}

// Fallback (only if ws_size is too small): fully fused, gathers h rows per edge.
__global__ void edge_fused_kernel(const float* __restrict__ h,
                                  const float* __restrict__ e,
                                  const int* __restrict__ src,
                                  const int* __restrict__ dst,
                                  const float* __restrict__ W,
                                  const float* __restrict__ b,
                                  float* __restrict__ out,
                                  int n_edges) {
    int tid  = blockIdx.x * blockDim.x + threadIdx.x;
    int edge = tid >> 5;
    int l    = tid & 31;
    if (edge >= n_edges) return;

    int s_idx = src[edge];
    int d_idx = dst[edge];

    const float4 hk = *reinterpret_cast<const float4*>(h + (size_t)s_idx * DIM + 4 * l);
    const float4 hi = *reinterpret_cast<const float4*>(h + (size_t)d_idx * DIM + 4 * l);
    const float4 ev = *reinterpret_cast<const float4*>(e + (size_t)edge * DIM + 4 * l);
    const float4 wk = *reinterpret_cast<const float4*>(W + 4 * l);
    const float4 wi = *reinterpret_cast<const float4*>(W + DIM + 4 * l);
    const float4 we = *reinterpret_cast<const float4*>(W + 2 * DIM + 4 * l);

    float s = hk.x * wk.x + hk.y * wk.y + hk.z * wk.z + hk.w * wk.w
            + hi.x * wi.x + hi.y * wi.y + hi.z * wi.z + hi.w * wi.w
            + ev.x * we.x + ev.y * we.y + ev.z * we.z + ev.w * we.w;
    s += __shfl_xor(s, 1);
    s += __shfl_xor(s, 2);
    s += __shfl_xor(s, 4);
    s += __shfl_xor(s, 8);
    s += __shfl_xor(s, 16);

    if (l == 0) {
        float logit = s + b[0];
        out[edge] = 1.0f / (1.0f + expf(-logit));
    }
}

extern "C" void kernel_launch(void* const* d_in, const int* in_sizes, int n_in,
                              void* d_out, int out_size, void* d_ws, size_t ws_size,
                              hipStream_t stream) {
    const float* h   = (const float*)d_in[0];
    const float* e   = (const float*)d_in[1];
    const int*   src = (const int*)d_in[2];
    const int*   dst = (const int*)d_in[3];
    const float* W   = (const float*)d_in[4];
    const float* b   = (const float*)d_in[5];
    float* out = (float*)d_out;

    const int n_nodes = in_sizes[0] / DIM;
    const int n_edges = in_sizes[2];

    const size_t ws_needed = 2 * (size_t)n_nodes * sizeof(float);

    if (ws_size >= ws_needed) {
        float* pk = (float*)d_ws;
        float* pi = pk + n_nodes;

        {
            const int block = 256;
            // 16 lanes per node, 4 nodes per group-iteration
            long total = ((long)n_nodes + 3) / 4 * 16;
            int grid = (int)((total + block - 1) / block);
            if (grid > 2048) grid = 2048;
            node_proj_kernel<<<grid, block, 0, stream>>>(h, W, pk, pi, n_nodes);
        }
        {
            const int block = 256;
            long total = ((long)n_edges + 3) / 4 * 16;
            int grid = (int)((total + block - 1) / block);
            if (grid > 2048) grid = 2048;
            edge_kernel<<<grid, block, 0, stream>>>(e, src, dst, W, b, pk, pi, out, n_edges);
        }
    } else {
        int total = n_edges * 32;
        int block = 256;
        int grid  = (total + block - 1) / block;
        edge_fused_kernel<<<grid, block, 0, stream>>>(h, e, src, dst, W, b, out, n_edges);
    }
}